// Round 2
// baseline (99.897 us; speedup 1.0000x reference)
//
#include <hip/hip_runtime.h>
#include <hip/hip_bf16.h>

// Problem: B=64, P=128, D=1024  (all fp32)
//   s[b,p] = dot(concat(h[b,p],q[b,p]), W_att) + b_att   (uniform -> cancels in softmax)
//   a      = softmax_P(s)
//   out[b] = sum_p a[b,p] * dot(concat(h,q), W_fc) + b_fc

#define BB 64
#define PP 128
#define DD 1024

// Stage 1: one block (256 thr) per (b,p) row; compute both dots in fp32.
// Thread t<128 covers h-half, t>=128 covers q-half; each thread reads
// 2 float4 chunks (8 floats) of its 1024-float half -> fully coalesced 16B/lane.
__global__ __launch_bounds__(256) void score_kernel(
    const float* __restrict__ h,
    const float* __restrict__ q,
    const float* __restrict__ Watt,
    const float* __restrict__ Wfc,
    float* __restrict__ s_out, float* __restrict__ t_out)
{
    const int r   = blockIdx.x;        // b*PP + p
    const int tid = threadIdx.x;       // 0..255
    const bool isq = tid >= 128;
    const int j = tid & 127;           // float4-chunk lane within half

    const float* row = (isq ? q : h) + (size_t)r * DD;
    const float* wa  = Watt + (isq ? DD : 0);
    const float* wf  = Wfc  + (isq ? DD : 0);

    const float4* row4 = (const float4*)row;
    const float4* wa4  = (const float4*)wa;
    const float4* wf4  = (const float4*)wf;

    float s_acc = 0.f, t_acc = 0.f;
    #pragma unroll
    for (int c = 0; c < 2; ++c) {
        const int idx = j + c * 128;   // 256 float4 chunks per 1024-float half
        float4 x = row4[idx];
        float4 a = wa4[idx];
        float4 f = wf4[idx];
        s_acc += x.x*a.x + x.y*a.y + x.z*a.z + x.w*a.w;
        t_acc += x.x*f.x + x.y*f.y + x.z*f.z + x.w*f.w;
    }

    // wave(64) shuffle reduce, both accumulators
    #pragma unroll
    for (int off = 32; off > 0; off >>= 1) {
        s_acc += __shfl_down(s_acc, off, 64);
        t_acc += __shfl_down(t_acc, off, 64);
    }

    __shared__ float sh_s[4], sh_t[4];
    const int wave = tid >> 6;
    if ((tid & 63) == 0) { sh_s[wave] = s_acc; sh_t[wave] = t_acc; }
    __syncthreads();
    if (tid == 0) {
        s_out[r] = sh_s[0] + sh_s[1] + sh_s[2] + sh_s[3];
        t_out[r] = sh_t[0] + sh_t[1] + sh_t[2] + sh_t[3];
    }
}

// Stage 2: one block per batch; softmax over P=128 + weighted pool.
__global__ __launch_bounds__(128) void softmax_pool_kernel(
    const float* __restrict__ s_in, const float* __restrict__ t_in,
    const float* __restrict__ b_fc,
    float* __restrict__ out)
{
    const int b = blockIdx.x;
    const int p = threadIdx.x;          // 0..127 (2 waves)
    const float s = s_in[b * PP + p];
    const float t = t_in[b * PP + p];

    // block max
    float m = s;
    #pragma unroll
    for (int off = 32; off > 0; off >>= 1) m = fmaxf(m, __shfl_down(m, off, 64));
    __shared__ float sh_m[2];
    if ((p & 63) == 0) sh_m[p >> 6] = m;
    __syncthreads();
    m = fmaxf(sh_m[0], sh_m[1]);

    float e   = __expf(s - m);
    float num = e * t;
    #pragma unroll
    for (int off = 32; off > 0; off >>= 1) {
        e   += __shfl_down(e, off, 64);
        num += __shfl_down(num, off, 64);
    }
    __shared__ float sh_z[2], sh_n[2];
    if ((p & 63) == 0) { sh_z[p >> 6] = e; sh_n[p >> 6] = num; }
    __syncthreads();
    if (p == 0) {
        const float Z = sh_z[0] + sh_z[1];
        const float N = sh_n[0] + sh_n[1];
        out[b] = N / Z + b_fc[0];
    }
}

extern "C" void kernel_launch(void* const* d_in, const int* in_sizes, int n_in,
                              void* d_out, int out_size, void* d_ws, size_t ws_size,
                              hipStream_t stream) {
    const float* h     = (const float*)d_in[0];
    const float* q     = (const float*)d_in[1];
    const float* W_att = (const float*)d_in[2];
    // d_in[3] = b_att (uniform, cancels in softmax)
    const float* W_fc  = (const float*)d_in[4];
    const float* b_fc  = (const float*)d_in[5];

    float* s_ws = (float*)d_ws;                 // B*P floats
    float* t_ws = s_ws + BB * PP;               // B*P floats

    score_kernel<<<BB * PP, 256, 0, stream>>>(h, q, W_att, W_fc, s_ws, t_ws);
    softmax_pool_kernel<<<BB, 128, 0, stream>>>(s_ws, t_ws, b_fc, (float*)d_out);
}